// Round 4
// baseline (559.738 us; speedup 1.0000x reference)
//
#include <hip/hip_runtime.h>
#include <math.h>

// LSTM B=1024,T=512,IN=16,H=64,OUT=8, gates i,f,g,o.
// R4: single-barrier step. Re-tiled MFMA: tile tt = GATE TYPE, rows
// tt*64 + 16w + m, so lane (q,mcol) holds i,f,g,o preacts for
// (j=16w+4q+r, batch=mcol) in acc[0..3][r] -> activation + c-update fully
// in-register (R3's cross-wave pre[] round-trip + 2nd barrier removed;
// its 1.7e7 LDS conflict cycles came from those 1024B-strided stores).
// xh (bf16 x|h|pad per batch) double-buffered -> 1 __syncthreads per step.
// Weights: split bf16 hi+lo A-frags pinned in regs (compiler remats
// otherwise, see R1/R2). BT=2 batches/block, 512 blocks, 2 blocks/CU.

#define LSTM_T 512
#define LSTM_IN 16
#define LSTM_H 64
#define LSTM_G 256
#define LSTM_OUT 8
#define BT 2
#define XH 96              // shorts per batch row: 16 x | 64 h | 16 zero pad

typedef short  short8  __attribute__((ext_vector_type(8)));
typedef float  floatx4 __attribute__((ext_vector_type(4)));

static __device__ __forceinline__ unsigned f2bf(float f) {
    unsigned u = __float_as_uint(f);
    return (u + 0x7FFFu + ((u >> 16) & 1u)) >> 16;   // RNE f32 -> bf16
}
static __device__ __forceinline__ float bf2f(unsigned s) {
    return __uint_as_float(s << 16);
}
static __device__ __forceinline__ float fast_rcp(float x) { return __builtin_amdgcn_rcpf(x); }
static __device__ __forceinline__ float sigm(float x) { return fast_rcp(1.0f + __expf(-x)); }
static __device__ __forceinline__ float tanh_(float x) {
    float a = fminf(-2.0f * x, 80.0f);
    float e = __expf(a);
    return (1.0f - e) * fast_rcp(1.0f + e);
}
static __device__ __forceinline__ void pin4(int4& v) {
    asm volatile("" : "+v"(v.x), "+v"(v.y), "+v"(v.z), "+v"(v.w));
}
static __device__ __forceinline__ void pinf4(float4& v) {
    asm volatile("" : "+v"(v.x), "+v"(v.y), "+v"(v.z), "+v"(v.w));
}

// 8 floats -> split bf16 hi/lo packed as int4 (element j = short j)
static __device__ __forceinline__ void cvt8(float4 a, float4 b, int4& hi, int4& lo) {
    float f[8] = {a.x, a.y, a.z, a.w, b.x, b.y, b.z, b.w};
    unsigned h[8], l[8];
    #pragma unroll
    for (int j = 0; j < 8; ++j) {
        h[j] = f2bf(f[j]);
        l[j] = f2bf(f[j] - bf2f(h[j]));
    }
    hi = make_int4((int)(h[0] | (h[1] << 16)), (int)(h[2] | (h[3] << 16)),
                   (int)(h[4] | (h[5] << 16)), (int)(h[6] | (h[7] << 16)));
    lo = make_int4((int)(l[0] | (l[1] << 16)), (int)(l[2] | (l[3] << 16)),
                   (int)(l[4] | (l[5] << 16)), (int)(l[6] | (l[7] << 16)));
}

__global__ __launch_bounds__(256, 2)
void lstm_mfma_kernel(const float* __restrict__ x,
                      const float* __restrict__ W_ih,
                      const float* __restrict__ W_hh,
                      const float* __restrict__ b_ih,
                      const float* __restrict__ b_hh,
                      const float* __restrict__ W_fc,
                      const float* __restrict__ b_fc,
                      float* __restrict__ out) {
    const int tid   = threadIdx.x;
    const int lane  = tid & 63;
    const int w     = tid >> 6;       // wave -> j-slice [16w, 16w+16)
    const int q     = lane >> 4;      // k-quad / C row group (j = 16w+4q+r)
    const int mcol  = lane & 15;      // A row-in-tile / C col (batch)
    const int nb    = lane & 1;       // B-frag replicated batch column
    const int bbase = blockIdx.x * BT;

    __shared__ __align__(16) short xhbuf[2][BT][XH];   // double-buffered x|h|pad
    __shared__ __align__(16) float hfin[BT][LSTM_H];   // final h for FC

    // ---- weights as pinned split-bf16 A-fragments ----
    // tile tt = gate type; A row = tt*64 + 16w + mcol.
    // K layout: k0-15 = W_ih row, k16-79 = W_hh row, k80-95 = 0.
    int4 Ahi[4][3], Alo[4][3];
    float4 bias4[4];
    #pragma unroll
    for (int tt = 0; tt < 4; ++tt) {
        const int gt = tt * 64 + 16 * w + mcol;
        #pragma unroll
        for (int c = 0; c < 3; ++c) {
            const float* src = nullptr;
            if (c == 0)      src = (q < 2) ? (W_ih + gt * LSTM_IN + 8 * q)
                                           : (W_hh + gt * LSTM_H + 8 * (q - 2));
            else if (c == 1) src = W_hh + gt * LSTM_H + 16 + 8 * q;
            else if (q < 2)  src = W_hh + gt * LSTM_H + 48 + 8 * q;
            float4 a = make_float4(0.f, 0.f, 0.f, 0.f);
            float4 b = make_float4(0.f, 0.f, 0.f, 0.f);
            if (src) {
                a = *reinterpret_cast<const float4*>(src);
                b = *reinterpret_cast<const float4*>(src + 4);
            }
            cvt8(a, b, Ahi[tt][c], Alo[tt][c]);
            pin4(Ahi[tt][c]);
            pin4(Alo[tt][c]);
        }
        const int gb = tt * 64 + 16 * w + 4 * q;       // gates for C regs r=0..3
        float4 bi = *reinterpret_cast<const float4*>(b_ih + gb);
        float4 bh = *reinterpret_cast<const float4*>(b_hh + gb);
        bias4[tt] = make_float4(bi.x + bh.x, bi.y + bh.y, bi.z + bh.z, bi.w + bh.w);
        pinf4(bias4[tt]);
    }

    // ---- init: zero both buffers, then x(t=0) into buf0 ----
    if (tid < 192) reinterpret_cast<int*>(xhbuf)[tid] = 0;   // 768 B
    __syncthreads();
    if (tid < BT * LSTM_IN) {
        int b = tid >> 4, i = tid & 15;
        xhbuf[0][b][i] = (short)f2bf(x[(size_t)(bbase + b) * LSTM_T * LSTM_IN + i]);
    }
    __syncthreads();

    float creg[4] = {0.f, 0.f, 0.f, 0.f};
    float hreg[4] = {0.f, 0.f, 0.f, 0.f};

    for (int t = 0; t < LSTM_T; ++t) {
        short (*cur)[XH] = xhbuf[t & 1];
        short (*nxt)[XH] = xhbuf[(t + 1) & 1];

        // prefetch x_{t+1} (global latency hidden behind mfma+act)
        float xnext = 0.0f;
        if (tid < BT * LSTM_IN && t + 1 < LSTM_T) {
            int b = tid >> 4, i = tid & 15;
            xnext = x[(size_t)(bbase + b) * LSTM_T * LSTM_IN + (t + 1) * LSTM_IN + i];
        }

        // B-fragments: col n holds batch n&1 (valid duplicates), conflict-free
        short8 bfr[3];
        const short* base = &cur[nb][0];
        #pragma unroll
        for (int c = 0; c < 3; ++c)
            bfr[c] = *reinterpret_cast<const short8*>(base + 32 * c + 8 * q);

        // G = W_hi.xh + W_lo.xh + bias
        floatx4 acc[4];
        #pragma unroll
        for (int tt = 0; tt < 4; ++tt) {
            acc[tt][0] = bias4[tt].x; acc[tt][1] = bias4[tt].y;
            acc[tt][2] = bias4[tt].z; acc[tt][3] = bias4[tt].w;
        }
        #pragma unroll
        for (int c = 0; c < 3; ++c) {
            #pragma unroll
            for (int tt = 0; tt < 4; ++tt)
                acc[tt] = __builtin_amdgcn_mfma_f32_16x16x32_bf16(
                    __builtin_bit_cast(short8, Ahi[tt][c]), bfr[c], acc[tt], 0, 0, 0);
            #pragma unroll
            for (int tt = 0; tt < 4; ++tt)
                acc[tt] = __builtin_amdgcn_mfma_f32_16x16x32_bf16(
                    __builtin_bit_cast(short8, Alo[tt][c]), bfr[c], acc[tt], 0, 0, 0);
        }

        // in-lane activation + state update: acc[tt][r] = gate tt of
        // (j = 16w+4q+r, batch = mcol)
        #pragma unroll
        for (int r = 0; r < 4; ++r) {
            float gi = sigm(acc[0][r]);
            float gf = sigm(acc[1][r]);
            float gg = tanh_(acc[2][r]);
            float go = sigm(acc[3][r]);
            creg[r] = fmaf(gf, creg[r], gi * gg);
            hreg[r] = go * tanh_(creg[r]);
        }

        // h -> next buffer as bf16 (4 consecutive shorts, 8B-aligned)
        if (mcol < BT) {
            unsigned p0 = f2bf(hreg[0]) | (f2bf(hreg[1]) << 16);
            unsigned p1 = f2bf(hreg[2]) | (f2bf(hreg[3]) << 16);
            *reinterpret_cast<uint2*>(&nxt[mcol][LSTM_IN + 16 * w + 4 * q]) =
                make_uint2(p0, p1);
        }
        // x_{t+1} -> next buffer
        if (tid < BT * LSTM_IN) nxt[tid >> 4][tid & 15] = (short)f2bf(xnext);

        __syncthreads();   // single barrier: nxt complete before next step reads
    }

    // ---- final h to LDS, then FC + sigmoid ----
    if (mcol < BT) {
        *reinterpret_cast<float4*>(&hfin[mcol][16 * w + 4 * q]) =
            make_float4(hreg[0], hreg[1], hreg[2], hreg[3]);
    }
    __syncthreads();

    if (tid < BT * LSTM_OUT) {
        int b = tid >> 3, o = tid & 7;
        float s = b_fc[o];
        #pragma unroll 8
        for (int j = 0; j < LSTM_H; ++j) s = fmaf(W_fc[o * LSTM_H + j], hfin[b][j], s);
        out[(size_t)(bbase + b) * LSTM_OUT + o] = sigm(s);
    }
}

extern "C" void kernel_launch(void* const* d_in, const int* in_sizes, int n_in,
                              void* d_out, int out_size, void* d_ws, size_t ws_size,
                              hipStream_t stream) {
    const float* x    = (const float*)d_in[0];
    const float* W_ih = (const float*)d_in[1];
    const float* W_hh = (const float*)d_in[2];
    const float* b_ih = (const float*)d_in[3];
    const float* b_hh = (const float*)d_in[4];
    const float* W_fc = (const float*)d_in[5];
    const float* b_fc = (const float*)d_in[6];
    float* out = (float*)d_out;

    lstm_mfma_kernel<<<1024 / BT, 256, 0, stream>>>(
        x, W_ih, W_hh, b_ih, b_hh, W_fc, b_fc, out);
}

// Round 5
// 365.708 us; speedup vs baseline: 1.5306x; 1.5306x over previous
//
#include <hip/hip_runtime.h>
#include <math.h>

// LSTM B=1024,T=512,IN=16,H=64,OUT=8, gates i,f,g,o.
// R5: BT=16 — every MFMA column is a real batch, so R4's in-lane activation
// has ZERO redundant issue (R4@BT=2 wasted 14/16 columns -> VALUBusy 65%,
// 560us). 64 blocks x 256 thr (4 waves), 1 block/CU, 1 wave/SIMD.
// Wave w owns j-slice [16w,16w+16); tiles tt = gate type, A rows
// tt*64+16w+mcol; C: lane(q,mcol) holds gate tt of (j=16w+4q+r, b=mcol)
// in acc[tt][r] -> activation + c/h update fully in-register.
// log2e folded into weights/biases: i,f,o rows x log2e, g rows x 2*log2e
// => sigmoid = rcp(1+exp2(-pre)), tanh = 1-2*rcp(1+exp2(pre)). Split-bf16
// (hi+lo) weights pinned in regs. xh double-buffered, 1 barrier/step.

#define LSTM_T 512
#define LSTM_IN 16
#define LSTM_H 64
#define LSTM_OUT 8
#define BT 16
#define XH 96              // shorts per batch row: 16 x | 64 h | 16 zero pad

#define L2E   1.44269504088896340736f
#define L2E2  2.88539008177792681472f

typedef short  short8  __attribute__((ext_vector_type(8)));
typedef float  floatx4 __attribute__((ext_vector_type(4)));

static __device__ __forceinline__ unsigned f2bf(float f) {
    unsigned u = __float_as_uint(f);
    return (u + 0x7FFFu + ((u >> 16) & 1u)) >> 16;   // RNE f32 -> bf16
}
static __device__ __forceinline__ float bf2f(unsigned s) {
    return __uint_as_float(s << 16);
}
static __device__ __forceinline__ float fast_rcp(float x) { return __builtin_amdgcn_rcpf(x); }
static __device__ __forceinline__ float fast_exp2(float x) { return __builtin_amdgcn_exp2f(x); }
// pre already scaled by log2e:
static __device__ __forceinline__ float sigm2(float pre) {
    return fast_rcp(1.0f + fast_exp2(-pre));
}
// pre already scaled by 2*log2e: tanh = 1 - 2/(1+2^pre)
static __device__ __forceinline__ float tanh2(float pre) {
    return fmaf(-2.0f, fast_rcp(1.0f + fast_exp2(pre)), 1.0f);
}
static __device__ __forceinline__ void pin4(int4& v) {
    asm volatile("" : "+v"(v.x), "+v"(v.y), "+v"(v.z), "+v"(v.w));
}
static __device__ __forceinline__ void pinf4(float4& v) {
    asm volatile("" : "+v"(v.x), "+v"(v.y), "+v"(v.z), "+v"(v.w));
}

// 8 floats (pre-scaled) -> split bf16 hi/lo packed as int4
static __device__ __forceinline__ void cvt8(float4 a, float4 b, int4& hi, int4& lo) {
    float f[8] = {a.x, a.y, a.z, a.w, b.x, b.y, b.z, b.w};
    unsigned h[8], l[8];
    #pragma unroll
    for (int j = 0; j < 8; ++j) {
        h[j] = f2bf(f[j]);
        l[j] = f2bf(f[j] - bf2f(h[j]));
    }
    hi = make_int4((int)(h[0] | (h[1] << 16)), (int)(h[2] | (h[3] << 16)),
                   (int)(h[4] | (h[5] << 16)), (int)(h[6] | (h[7] << 16)));
    lo = make_int4((int)(l[0] | (l[1] << 16)), (int)(l[2] | (l[3] << 16)),
                   (int)(l[4] | (l[5] << 16)), (int)(l[6] | (l[7] << 16)));
}

__global__ __launch_bounds__(256, 1)
void lstm_mfma_kernel(const float* __restrict__ x,
                      const float* __restrict__ W_ih,
                      const float* __restrict__ W_hh,
                      const float* __restrict__ b_ih,
                      const float* __restrict__ b_hh,
                      const float* __restrict__ W_fc,
                      const float* __restrict__ b_fc,
                      float* __restrict__ out) {
    const int tid   = threadIdx.x;
    const int lane  = tid & 63;
    const int w     = tid >> 6;       // wave -> j-slice [16w, 16w+16)
    const int q     = lane >> 4;      // k-quad / C row group (j = 16w+4q+r)
    const int mcol  = lane & 15;      // A row-in-tile / B col / C col (batch)
    const int bbase = blockIdx.x * BT;

    __shared__ __align__(16) short xhbuf[2][BT][XH];   // double-buffered x|h|pad (bf16)
    __shared__ __align__(16) float hfin[BT][LSTM_H];   // final h for FC

    // ---- weights as pinned split-bf16 A-fragments, log2e-folded ----
    // tile tt = gate type; A row = tt*64 + 16w + mcol.
    // K layout: k0-15 = W_ih row, k16-79 = W_hh row, k80-95 = 0.
    int4 Ahi[4][3], Alo[4][3];
    float4 bias4[4];
    #pragma unroll
    for (int tt = 0; tt < 4; ++tt) {
        const float sc = (tt == 2) ? L2E2 : L2E;
        const int gt = tt * 64 + 16 * w + mcol;
        #pragma unroll
        for (int c = 0; c < 3; ++c) {
            const float* src = nullptr;
            if (c == 0)      src = (q < 2) ? (W_ih + gt * LSTM_IN + 8 * q)
                                           : (W_hh + gt * LSTM_H + 8 * (q - 2));
            else if (c == 1) src = W_hh + gt * LSTM_H + 16 + 8 * q;
            else if (q < 2)  src = W_hh + gt * LSTM_H + 48 + 8 * q;
            float4 a = make_float4(0.f, 0.f, 0.f, 0.f);
            float4 b = make_float4(0.f, 0.f, 0.f, 0.f);
            if (src) {
                a = *reinterpret_cast<const float4*>(src);
                b = *reinterpret_cast<const float4*>(src + 4);
            }
            a.x *= sc; a.y *= sc; a.z *= sc; a.w *= sc;
            b.x *= sc; b.y *= sc; b.z *= sc; b.w *= sc;
            cvt8(a, b, Ahi[tt][c], Alo[tt][c]);
            pin4(Ahi[tt][c]);
            pin4(Alo[tt][c]);
        }
        const int gb = tt * 64 + 16 * w + 4 * q;       // gates for C regs r=0..3
        float4 bi = *reinterpret_cast<const float4*>(b_ih + gb);
        float4 bh = *reinterpret_cast<const float4*>(b_hh + gb);
        bias4[tt] = make_float4((bi.x + bh.x) * sc, (bi.y + bh.y) * sc,
                                (bi.z + bh.z) * sc, (bi.w + bh.w) * sc);
        pinf4(bias4[tt]);
    }

    // ---- init: zero both buffers (h=0, pad=0), then x(t=0) into buf0 ----
    {
        int* z = reinterpret_cast<int*>(xhbuf);        // 2*16*96 shorts = 1536 ints
        #pragma unroll
        for (int k = 0; k < 6; ++k) z[tid + 256 * k] = 0;
    }
    __syncthreads();
    {   // x(t=0): thread (b=tid>>4, i=tid&15)
        int b = tid >> 4, i = tid & 15;
        xhbuf[0][b][i] = (short)f2bf(x[(size_t)(bbase + b) * LSTM_T * LSTM_IN + i]);
    }
    __syncthreads();

    float creg[4] = {0.f, 0.f, 0.f, 0.f};
    float hreg[4] = {0.f, 0.f, 0.f, 0.f};

    for (int t = 0; t < LSTM_T; ++t) {
        short (*cur)[XH] = xhbuf[t & 1];
        short (*nxt)[XH] = xhbuf[(t + 1) & 1];

        // prefetch x_{t+1}: every thread loads 1 float (16 b x 16 i)
        float xnext = 0.0f;
        {
            int b = tid >> 4, i = tid & 15;
            if (t + 1 < LSTM_T)
                xnext = x[(size_t)(bbase + b) * LSTM_T * LSTM_IN + (t + 1) * LSTM_IN + i];
        }

        // B-fragments: col = mcol = batch (all 16 real), k-chunk = 8q
        short8 bfr[3];
        const short* base = &cur[mcol][0];
        #pragma unroll
        for (int c = 0; c < 3; ++c)
            bfr[c] = *reinterpret_cast<const short8*>(base + 32 * c + 8 * q);

        // G = W_hi.xh + W_lo.xh + bias (pre-activations, log2e-scaled)
        floatx4 acc[4];
        #pragma unroll
        for (int tt = 0; tt < 4; ++tt) {
            acc[tt][0] = bias4[tt].x; acc[tt][1] = bias4[tt].y;
            acc[tt][2] = bias4[tt].z; acc[tt][3] = bias4[tt].w;
        }
        #pragma unroll
        for (int c = 0; c < 3; ++c) {
            #pragma unroll
            for (int tt = 0; tt < 4; ++tt)
                acc[tt] = __builtin_amdgcn_mfma_f32_16x16x32_bf16(
                    __builtin_bit_cast(short8, Ahi[tt][c]), bfr[c], acc[tt], 0, 0, 0);
            #pragma unroll
            for (int tt = 0; tt < 4; ++tt)
                acc[tt] = __builtin_amdgcn_mfma_f32_16x16x32_bf16(
                    __builtin_bit_cast(short8, Alo[tt][c]), bfr[c], acc[tt], 0, 0, 0);
        }

        // in-lane activation + state: acc[tt][r] = gate tt of (j=16w+4q+r, b=mcol)
        #pragma unroll
        for (int r = 0; r < 4; ++r) {
            float gi = sigm2(acc[0][r]);
            float gf = sigm2(acc[1][r]);
            float gg = tanh2(acc[2][r]);
            float go = sigm2(acc[3][r]);
            creg[r] = fmaf(gf, creg[r], gi * gg);
            hreg[r] = go * tanh2(creg[r] * L2E2);
        }

        // h -> next buffer as bf16 (4 consecutive shorts, 8B aligned)
        {
            unsigned p0 = f2bf(hreg[0]) | (f2bf(hreg[1]) << 16);
            unsigned p1 = f2bf(hreg[2]) | (f2bf(hreg[3]) << 16);
            *reinterpret_cast<uint2*>(&nxt[mcol][LSTM_IN + 16 * w + 4 * q]) =
                make_uint2(p0, p1);
        }
        // x_{t+1} -> next buffer
        {
            int b = tid >> 4, i = tid & 15;
            nxt[b][i] = (short)f2bf(xnext);
        }
        __syncthreads();   // nxt complete before next step reads it
    }

    // ---- final h (fp32, from regs) -> LDS, then FC + sigmoid ----
    *reinterpret_cast<float4*>(&hfin[mcol][16 * w + 4 * q]) =
        make_float4(hreg[0], hreg[1], hreg[2], hreg[3]);
    __syncthreads();

    if (tid < BT * LSTM_OUT) {
        int b = tid >> 3, o = tid & 7;
        float s = b_fc[o];
        #pragma unroll 8
        for (int j = 0; j < LSTM_H; ++j) s = fmaf(W_fc[o * LSTM_H + j], hfin[b][j], s);
        out[(size_t)(bbase + b) * LSTM_OUT + o] = sigm2(s * L2E);
    }
}

extern "C" void kernel_launch(void* const* d_in, const int* in_sizes, int n_in,
                              void* d_out, int out_size, void* d_ws, size_t ws_size,
                              hipStream_t stream) {
    const float* x    = (const float*)d_in[0];
    const float* W_ih = (const float*)d_in[1];
    const float* W_hh = (const float*)d_in[2];
    const float* b_ih = (const float*)d_in[3];
    const float* b_hh = (const float*)d_in[4];
    const float* W_fc = (const float*)d_in[5];
    const float* b_fc = (const float*)d_in[6];
    float* out = (float*)d_out;

    lstm_mfma_kernel<<<1024 / BT, 256, 0, stream>>>(
        x, W_ih, W_hh, b_ih, b_hh, W_fc, b_fc, out);
}